// Round 1
// baseline (84.208 us; speedup 1.0000x reference)
//
#include <hip/hip_runtime.h>
#include <math.h>

#define N_G   512
#define W_IMG 256
#define H_IMG 256

// params layout per gaussian (3 x float4 = 48B), depth-sorted:
//  p0 = (mean_x, mean_y, qa, qb)      expo = qa*dx^2 + qb*dx*dy + qd*dy^2
//  p1 = (qd, w, r2cut, col_r)         w = valid * opac / (2*pi*sqrt(det))
//  p2 = (col_g, col_b, 0, 0)          skip tile if dist^2(rect, mean) > r2cut

__global__ __launch_bounds__(512) void project_sort_kernel(
    const float* __restrict__ means3D, const float* __restrict__ covs3d,
    const float* __restrict__ colors,  const float* __restrict__ opac,
    const float* __restrict__ Km, const float* __restrict__ Rm,
    const float* __restrict__ tv, float4* __restrict__ params_out)
{
    __shared__ float  s_key[N_G];
    __shared__ int    s_ord[N_G];
    __shared__ float4 s_par[N_G * 3];

    const int t = threadIdx.x;

    const float R00=Rm[0],R01=Rm[1],R02=Rm[2],
                R10=Rm[3],R11=Rm[4],R12=Rm[5],
                R20=Rm[6],R21=Rm[7],R22=Rm[8];
    const float K00=Km[0],K01=Km[1],K02=Km[2],
                K10=Km[3],K11=Km[4],K12=Km[5],
                K20=Km[6],K21=Km[7],K22=Km[8];
    const float t0=tv[0],t1=tv[1],t2=tv[2];

    const float m0=means3D[3*t], m1=means3D[3*t+1], m2=means3D[3*t+2];
    // cam = R*m + t
    const float cx = R00*m0 + R01*m1 + R02*m2 + t0;
    const float cy = R10*m0 + R11*m1 + R12*m2 + t1;
    const float cz = R20*m0 + R21*m1 + R22*m2 + t2;
    const float depth = fmaxf(cz, 1.0f);

    // screen = K*cam ; means2D = screen.xy / screen.z
    const float s0 = K00*cx + K01*cy + K02*cz;
    const float s1 = K10*cx + K11*cy + K12*cz;
    const float s2 = K20*cx + K21*cy + K22*cz;
    const float mx = s0 / s2;
    const float my = s1 / s2;

    // covs_cam = R * C * R^T
    const float C00=covs3d[9*t+0], C01=covs3d[9*t+1], C02=covs3d[9*t+2];
    const float C10=covs3d[9*t+3], C11=covs3d[9*t+4], C12=covs3d[9*t+5];
    const float C20=covs3d[9*t+6], C21=covs3d[9*t+7], C22=covs3d[9*t+8];

    float T00 = R00*C00 + R01*C10 + R02*C20;
    float T01 = R00*C01 + R01*C11 + R02*C21;
    float T02 = R00*C02 + R01*C12 + R02*C22;
    float T10 = R10*C00 + R11*C10 + R12*C20;
    float T11 = R10*C01 + R11*C11 + R12*C21;
    float T12 = R10*C02 + R11*C12 + R12*C22;
    float T20 = R20*C00 + R21*C10 + R22*C20;
    float T21 = R20*C01 + R21*C11 + R22*C21;
    float T22 = R20*C02 + R21*C12 + R22*C22;

    const float cc00 = T00*R00 + T01*R01 + T02*R02;
    const float cc01 = T00*R10 + T01*R11 + T02*R12;
    const float cc02 = T00*R20 + T01*R21 + T02*R22;
    const float cc10 = T10*R00 + T11*R01 + T12*R02;
    const float cc11 = T10*R10 + T11*R11 + T12*R12;
    const float cc12 = T10*R20 + T11*R21 + T12*R22;
    const float cc20 = T20*R00 + T21*R01 + T22*R02;
    const float cc21 = T20*R10 + T21*R11 + T22*R12;
    const float cc22 = T20*R20 + T21*R21 + T22*R22;

    // J rows (uses UNCLIPPED cz, like the reference)
    const float fx = K00, fy = K11;
    const float invz = 1.0f / cz;
    const float J00 = fx * invz;
    const float J02 = -fx * cx * invz * invz;
    const float J11 = fy * invz;
    const float J12 = -fy * cy * invz * invz;

    // U = J * covs_cam (2x3)
    const float U00 = J00*cc00 + J02*cc20;
    const float U01 = J00*cc01 + J02*cc21;
    const float U02 = J00*cc02 + J02*cc22;
    const float U10 = J11*cc10 + J12*cc20;
    const float U11 = J11*cc11 + J12*cc21;
    const float U12 = J11*cc12 + J12*cc22;

    // cov2D = U * J^T + 1e-4*I
    const float a = U00*J00 + U02*J02 + 1e-4f;
    const float b = U01*J11 + U02*J12;
    const float c = U10*J00 + U12*J02;
    const float d = U11*J11 + U12*J12 + 1e-4f;

    const float det = a*d - b*c;
    const float ia  = d / det;
    const float id_ = a / det;
    const float sib = (b + c) / det;   // = -(ib+ic)

    const float qa = -0.5f * ia;
    const float qb =  0.5f * sib;
    const float qd = -0.5f * id_;

    const bool valid = (depth > 1.0f) && (depth < 50.0f);
    const float norm = 0.15915494309189535f * rsqrtf(det) * (det > 0.f ? 1.f : 1.f); // 1/(2*pi*sqrt(det))
    float w = valid ? opac[t] * norm : 0.0f;
    if (!(w > 0.0f)) w = 0.0f;   // scrub possible NaN for invalid gaussians

    // lambda_min of conic Q = [[ia, sib/2],[sib/2, id_]] (note expo uses -(...))
    const float hm  = 0.5f * (ia + id_);
    const float dh  = 0.5f * (ia - id_);
    const float off = 0.5f * sib;
    const float lmin = hm - sqrtf(dh*dh + off*off);

    float r2cut;
    if (w <= 1e-9f)        r2cut = -1.0f;          // always skip
    else if (lmin <= 0.f)  r2cut = 1e30f;          // never skip (conservative)
    else                   r2cut = 2.0f * __logf(w * 1e9f) / lmin;

    s_key[t] = depth;
    s_ord[t] = t;
    s_par[t*3+0] = make_float4(mx, my, qa, qb);
    s_par[t*3+1] = make_float4(qd, w, r2cut, colors[3*t]);
    s_par[t*3+2] = make_float4(colors[3*t+1], colors[3*t+2], 0.f, 0.f);
    __syncthreads();

    // bitonic sort of (depth, orig_idx), idx tie-break == stable argsort
    for (int k = 2; k <= N_G; k <<= 1) {
        for (int j = k >> 1; j > 0; j >>= 1) {
            const int ixj = t ^ j;
            if (ixj > t) {
                const float ka = s_key[t], kb = s_key[ixj];
                const int   oa = s_ord[t], ob = s_ord[ixj];
                const bool up   = ((t & k) == 0);
                const bool agtb = (ka > kb) || (ka == kb && oa > ob);
                if (agtb == up) {
                    s_key[t] = kb; s_key[ixj] = ka;
                    s_ord[t] = ob; s_ord[ixj] = oa;
                }
            }
            __syncthreads();
        }
    }

    const int gi = s_ord[t];
    params_out[t*3+0] = s_par[gi*3+0];
    params_out[t*3+1] = s_par[gi*3+1];
    params_out[t*3+2] = s_par[gi*3+2];
}

__global__ __launch_bounds__(256) void render_kernel(
    const float4* __restrict__ params, float* __restrict__ out)
{
    __shared__ int    s_cnt[8];
    __shared__ int    s_off[9];
    __shared__ int    s_idx[N_G];
    __shared__ float4 s_p[N_G * 3];

    const int tid  = threadIdx.x;
    const int wave = tid >> 6;
    const int lane = tid & 63;
    const int x0 = blockIdx.x * 16;
    const int y0 = blockIdx.y * 16;
    const float rx0 = (float)x0, ry0 = (float)y0;
    const float rx1 = rx0 + 15.f, ry1 = ry0 + 15.f;

    // ---- cull: each wave tests groups {wave, wave+4} of 64 gaussians ----
    bool pass[2];
    unsigned long long mm[2];
    int gix[2];
    #pragma unroll
    for (int cgrp = 0; cgrp < 2; ++cgrp) {
        const int g = wave + 4 * cgrp;
        const int i = g * 64 + lane;
        gix[cgrp] = i;
        const float4 p0 = params[i*3];
        const float4 p1 = params[i*3+1];
        const float w = p1.y, r2cut = p1.z;
        const float cxp = fminf(fmaxf(p0.x, rx0), rx1);
        const float cyp = fminf(fmaxf(p0.y, ry0), ry1);
        const float ddx = p0.x - cxp, ddy = p0.y - cyp;
        const float d2 = ddx*ddx + ddy*ddy;
        pass[cgrp] = (w > 0.f) && (d2 <= r2cut);
        mm[cgrp] = __ballot(pass[cgrp]);
        if (lane == 0) s_cnt[g] = __popcll(mm[cgrp]);
    }
    __syncthreads();
    if (tid == 0) {
        int acc = 0;
        for (int g = 0; g < 8; ++g) { s_off[g] = acc; acc += s_cnt[g]; }
        s_off[8] = acc;
    }
    __syncthreads();
    #pragma unroll
    for (int cgrp = 0; cgrp < 2; ++cgrp) {
        const int g = wave + 4 * cgrp;
        if (pass[cgrp]) {
            const int rank = __popcll(mm[cgrp] & ((1ull << lane) - 1ull));
            s_idx[s_off[g] + rank] = gix[cgrp];
        }
    }
    __syncthreads();
    const int count = s_off[8];

    // ---- stage surviving gaussians (depth order preserved) into LDS ----
    for (int j = tid; j < count; j += 256) {
        const int gi = s_idx[j];
        s_p[j*3+0] = params[gi*3+0];
        s_p[j*3+1] = params[gi*3+1];
        s_p[j*3+2] = params[gi*3+2];
    }
    __syncthreads();

    // ---- composite front-to-back ----
    const float px = (float)(x0 + (tid & 15));
    const float py = (float)(y0 + (tid >> 4));
    float T = 1.f, accr = 0.f, accg = 0.f, accb = 0.f;

    #pragma unroll 2
    for (int j = 0; j < count; ++j) {
        const float4 p0 = s_p[j*3+0];
        const float4 p1 = s_p[j*3+1];
        const float4 p2 = s_p[j*3+2];
        const float dx = px - p0.x;
        const float dy = py - p0.y;
        const float e = (p0.z*dx + p0.w*dy)*dx + p1.x*dy*dy;
        const float alpha = p1.y * __expf(e);
        const float wt = alpha * T;
        accr = fmaf(wt, p1.w, accr);
        accg = fmaf(wt, p2.x, accg);
        accb = fmaf(wt, p2.y, accb);
        T *= (1.f - alpha);
    }

    const int o = ((y0 + (tid >> 4)) * W_IMG + (x0 + (tid & 15))) * 3;
    out[o+0] = accr;
    out[o+1] = accg;
    out[o+2] = accb;
}

extern "C" void kernel_launch(void* const* d_in, const int* in_sizes, int n_in,
                              void* d_out, int out_size, void* d_ws, size_t ws_size,
                              hipStream_t stream) {
    const float* means3D = (const float*)d_in[0];
    const float* covs3d  = (const float*)d_in[1];
    const float* colors  = (const float*)d_in[2];
    const float* opac    = (const float*)d_in[3];
    const float* Km      = (const float*)d_in[4];
    const float* Rm      = (const float*)d_in[5];
    const float* tv      = (const float*)d_in[6];
    // d_in[7] = pixels: exact integer meshgrid, regenerated in-kernel

    float4* params = (float4*)d_ws;          // 512 * 48B = 24.6 KB
    float*  out    = (float*)d_out;

    hipLaunchKernelGGL(project_sort_kernel, dim3(1), dim3(512), 0, stream,
                       means3D, covs3d, colors, opac, Km, Rm, tv, params);
    hipLaunchKernelGGL(render_kernel, dim3(16, 16), dim3(256), 0, stream,
                       params, out);
}

// Round 2
// 84.179 us; speedup vs baseline: 1.0003x; 1.0003x over previous
//
#include <hip/hip_runtime.h>
#include <math.h>

#define N_G   512
#define W_IMG 256
#define H_IMG 256

// params layout per gaussian (3 x float4 = 48B), depth-sorted:
//  p0 = (mean_x, mean_y, qa, qb)      expo = qa*dx^2 + qb*dx*dy + qd*dy^2
//  p1 = (qd, w, r2cut, col_r)         w = valid * opac / (2*pi*sqrt(det))
//  p2 = (col_g, col_b, 0, 0)          skip tile if dist^2(rect, mean) > r2cut

__global__ __launch_bounds__(512) void gs_project_rank(
    const float* __restrict__ means3D, const float* __restrict__ covs3d,
    const float* __restrict__ colors,  const float* __restrict__ opac,
    const float* __restrict__ Km, const float* __restrict__ Rm,
    const float* __restrict__ tv, float4* __restrict__ params_out)
{
    __shared__ unsigned int s_key[N_G];

    const int t = threadIdx.x;

    const float R00=Rm[0],R01=Rm[1],R02=Rm[2],
                R10=Rm[3],R11=Rm[4],R12=Rm[5],
                R20=Rm[6],R21=Rm[7],R22=Rm[8];
    const float K00=Km[0],K01=Km[1],K02=Km[2],
                K10=Km[3],K11=Km[4],K12=Km[5],
                K20=Km[6],K21=Km[7],K22=Km[8];
    const float t0=tv[0],t1=tv[1],t2=tv[2];

    const float m0=means3D[3*t], m1=means3D[3*t+1], m2=means3D[3*t+2];
    // cam = R*m + t
    const float cx = R00*m0 + R01*m1 + R02*m2 + t0;
    const float cy = R10*m0 + R11*m1 + R12*m2 + t1;
    const float cz = R20*m0 + R21*m1 + R22*m2 + t2;
    const float depth = fmaxf(cz, 1.0f);

    // screen = K*cam ; means2D = screen.xy / screen.z
    const float s0 = K00*cx + K01*cy + K02*cz;
    const float s1 = K10*cx + K11*cy + K12*cz;
    const float s2 = K20*cx + K21*cy + K22*cz;
    const float mx = s0 / s2;
    const float my = s1 / s2;

    // covs_cam = R * C * R^T
    const float C00=covs3d[9*t+0], C01=covs3d[9*t+1], C02=covs3d[9*t+2];
    const float C10=covs3d[9*t+3], C11=covs3d[9*t+4], C12=covs3d[9*t+5];
    const float C20=covs3d[9*t+6], C21=covs3d[9*t+7], C22=covs3d[9*t+8];

    float T00 = R00*C00 + R01*C10 + R02*C20;
    float T01 = R00*C01 + R01*C11 + R02*C21;
    float T02 = R00*C02 + R01*C12 + R02*C22;
    float T10 = R10*C00 + R11*C10 + R12*C20;
    float T11 = R10*C01 + R11*C11 + R12*C21;
    float T12 = R10*C02 + R11*C12 + R12*C22;
    float T20 = R20*C00 + R21*C10 + R22*C20;
    float T21 = R20*C01 + R21*C11 + R22*C21;
    float T22 = R20*C02 + R21*C12 + R22*C22;

    const float cc00 = T00*R00 + T01*R01 + T02*R02;
    const float cc01 = T00*R10 + T01*R11 + T02*R12;
    const float cc02 = T00*R20 + T01*R21 + T02*R22;
    const float cc10 = T10*R00 + T11*R01 + T12*R02;
    const float cc11 = T10*R10 + T11*R11 + T12*R12;
    const float cc12 = T10*R20 + T11*R21 + T12*R22;
    const float cc20 = T20*R00 + T21*R01 + T22*R02;
    const float cc21 = T20*R10 + T21*R11 + T22*R12;
    const float cc22 = T20*R20 + T21*R21 + T22*R22;

    // J rows (uses UNCLIPPED cz, like the reference)
    const float fx = K00, fy = K11;
    const float invz = 1.0f / cz;
    const float J00 = fx * invz;
    const float J02 = -fx * cx * invz * invz;
    const float J11 = fy * invz;
    const float J12 = -fy * cy * invz * invz;

    // U = J * covs_cam (2x3)
    const float U00 = J00*cc00 + J02*cc20;
    const float U01 = J00*cc01 + J02*cc21;
    const float U02 = J00*cc02 + J02*cc22;
    const float U10 = J11*cc10 + J12*cc20;
    const float U11 = J11*cc11 + J12*cc21;
    const float U12 = J11*cc12 + J12*cc22;

    // cov2D = U * J^T + 1e-4*I
    const float a = U00*J00 + U02*J02 + 1e-4f;
    const float b = U01*J11 + U02*J12;
    const float c = U10*J00 + U12*J02;
    const float d = U11*J11 + U12*J12 + 1e-4f;

    const float det = a*d - b*c;
    const float ia  = d / det;
    const float id_ = a / det;
    const float sib = (b + c) / det;   // = -(ib+ic)

    const float qa = -0.5f * ia;
    const float qb =  0.5f * sib;
    const float qd = -0.5f * id_;

    const bool valid = (depth > 1.0f) && (depth < 50.0f);
    const float norm = 0.15915494309189535f * rsqrtf(det); // 1/(2*pi*sqrt(det))
    float w = valid ? opac[t] * norm : 0.0f;
    if (!(w > 0.0f)) w = 0.0f;   // scrub possible NaN for invalid gaussians

    // lambda_min of conic Q = [[ia, sib/2],[sib/2, id_]]
    const float hm  = 0.5f * (ia + id_);
    const float dh  = 0.5f * (ia - id_);
    const float off = 0.5f * sib;
    const float lmin = hm - sqrtf(dh*dh + off*off);

    // cull threshold tau = 1e-7: worst-case accumulated error <= 512*tau = 5.1e-5,
    // ~10x under the 4.96e-4 absmax threshold.
    float r2cut;
    if (w <= 1e-7f)        r2cut = -1.0f;          // always skip
    else if (lmin <= 0.f)  r2cut = 1e30f;          // never skip (conservative)
    else                   r2cut = 2.0f * __logf(w * 1e7f) / lmin;

    // ---- rank-based stable sort by clipped depth (depth>0 -> bits monotone) ----
    const unsigned int kb = __float_as_uint(depth);
    s_key[t] = kb;
    __syncthreads();

    int rank = 0;
    const uint4* k4 = (const uint4*)s_key;
    #pragma unroll 4
    for (int j = 0; j < N_G / 4; ++j) {
        const uint4 k = k4[j];
        rank += (k.x < kb) + (k.y < kb) + (k.z < kb) + (k.w < kb);
    }
    // stable tie-break: earlier original index wins
    for (int j = 0; j < t; ++j)
        rank += (s_key[j] == kb);

    params_out[rank*3+0] = make_float4(mx, my, qa, qb);
    params_out[rank*3+1] = make_float4(qd, w, r2cut, colors[3*t]);
    params_out[rank*3+2] = make_float4(colors[3*t+1], colors[3*t+2], 0.f, 0.f);
}

__global__ __launch_bounds__(256) void gs_render(
    const float4* __restrict__ params, float* __restrict__ out)
{
    __shared__ int    s_cnt[8];
    __shared__ int    s_off[9];
    __shared__ int    s_idx[N_G];
    __shared__ float4 s_p[N_G * 3];

    const int tid  = threadIdx.x;
    const int wave = tid >> 6;
    const int lane = tid & 63;
    const int x0 = blockIdx.x * 16;
    const int y0 = blockIdx.y * 16;
    const float rx0 = (float)x0, ry0 = (float)y0;
    const float rx1 = rx0 + 15.f, ry1 = ry0 + 15.f;

    // ---- cull: each wave tests groups {wave, wave+4} of 64 gaussians ----
    bool pass[2];
    unsigned long long mm[2];
    int gix[2];
    #pragma unroll
    for (int cgrp = 0; cgrp < 2; ++cgrp) {
        const int g = wave + 4 * cgrp;
        const int i = g * 64 + lane;
        gix[cgrp] = i;
        const float4 p0 = params[i*3];
        const float4 p1 = params[i*3+1];
        const float w = p1.y, r2cut = p1.z;
        const float cxp = fminf(fmaxf(p0.x, rx0), rx1);
        const float cyp = fminf(fmaxf(p0.y, ry0), ry1);
        const float ddx = p0.x - cxp, ddy = p0.y - cyp;
        const float d2 = ddx*ddx + ddy*ddy;
        pass[cgrp] = (w > 0.f) && (d2 <= r2cut);
        mm[cgrp] = __ballot(pass[cgrp]);
        if (lane == 0) s_cnt[g] = __popcll(mm[cgrp]);
    }
    __syncthreads();
    if (tid == 0) {
        int acc = 0;
        for (int g = 0; g < 8; ++g) { s_off[g] = acc; acc += s_cnt[g]; }
        s_off[8] = acc;
    }
    __syncthreads();
    #pragma unroll
    for (int cgrp = 0; cgrp < 2; ++cgrp) {
        const int g = wave + 4 * cgrp;
        if (pass[cgrp]) {
            const int rank = __popcll(mm[cgrp] & ((1ull << lane) - 1ull));
            s_idx[s_off[g] + rank] = gix[cgrp];
        }
    }
    __syncthreads();
    const int count = s_off[8];

    // ---- stage surviving gaussians (depth order preserved) into LDS ----
    for (int j = tid; j < count; j += 256) {
        const int gi = s_idx[j];
        s_p[j*3+0] = params[gi*3+0];
        s_p[j*3+1] = params[gi*3+1];
        s_p[j*3+2] = params[gi*3+2];
    }
    __syncthreads();

    // ---- composite front-to-back ----
    const float px = (float)(x0 + (tid & 15));
    const float py = (float)(y0 + (tid >> 4));
    float T = 1.f, accr = 0.f, accg = 0.f, accb = 0.f;

    #pragma unroll 4
    for (int j = 0; j < count; ++j) {
        const float4 p0 = s_p[j*3+0];
        const float4 p1 = s_p[j*3+1];
        const float4 p2 = s_p[j*3+2];
        const float dx = px - p0.x;
        const float dy = py - p0.y;
        const float e = (p0.z*dx + p0.w*dy)*dx + p1.x*dy*dy;
        const float alpha = p1.y * __expf(e);
        const float wt = alpha * T;
        accr = fmaf(wt, p1.w, accr);
        accg = fmaf(wt, p2.x, accg);
        accb = fmaf(wt, p2.y, accb);
        T = fmaf(-alpha, T, T);
    }

    const int o = ((y0 + (tid >> 4)) * W_IMG + (x0 + (tid & 15))) * 3;
    out[o+0] = accr;
    out[o+1] = accg;
    out[o+2] = accb;
}

extern "C" void kernel_launch(void* const* d_in, const int* in_sizes, int n_in,
                              void* d_out, int out_size, void* d_ws, size_t ws_size,
                              hipStream_t stream) {
    const float* means3D = (const float*)d_in[0];
    const float* covs3d  = (const float*)d_in[1];
    const float* colors  = (const float*)d_in[2];
    const float* opac    = (const float*)d_in[3];
    const float* Km      = (const float*)d_in[4];
    const float* Rm      = (const float*)d_in[5];
    const float* tv      = (const float*)d_in[6];
    // d_in[7] = pixels: exact integer meshgrid, regenerated in-kernel

    float4* params = (float4*)d_ws;          // 512 * 48B = 24.6 KB
    float*  out    = (float*)d_out;

    hipLaunchKernelGGL(gs_project_rank, dim3(1), dim3(512), 0, stream,
                       means3D, covs3d, colors, opac, Km, Rm, tv, params);
    hipLaunchKernelGGL(gs_render, dim3(16, 16), dim3(256), 0, stream,
                       params, out);
}